// Round 3
// baseline (807.013 us; speedup 1.0000x reference)
//
#include <hip/hip_runtime.h>
#include <hip/hip_bf16.h>

typedef _Float16 half8 __attribute__((ext_vector_type(8)));
typedef float f32x4 __attribute__((ext_vector_type(4)));

#define SS 200
#define HH 128
#define NHD 4
#define FH 512
#define NTILES 32   // FH/16
#define NEGF (-4294967295.0f)

// ---------------- pre-kernel: W1 [128][512] f32 -> fp16, MFMA-B-fragment-linear ----------------
// element ((nt*4 + ks)*64 + lane)*8 + j  holds  W1[ks*32 + (lane>>4)*8 + j][nt*16 + (lane&15)]
__global__ void swizzle_w1(const float* __restrict__ W1, _Float16* __restrict__ dst) {
    int tid = blockIdx.x * blockDim.x + threadIdx.x;   // 0..65535
    int j    = tid & 7;
    int lane = (tid >> 3) & 63;
    int ks   = (tid >> 9) & 3;
    int nt   = tid >> 11;
    int k = ks * 32 + (lane >> 4) * 8 + j;
    int n = nt * 16 + (lane & 15);
    dst[tid] = (_Float16)W1[k * FH + n];
}

__device__ __forceinline__ float tanh_fast(float x) {
    x = fminf(fmaxf(x, -15.0f), 15.0f);
    float e = __expf(x + x);
    return (e - 1.0f) * __builtin_amdgcn_rcpf(e + 1.0f);
}

__device__ __forceinline__ f32x4 mfma16(half8 a, half8 b, f32x4 c) {
    return __builtin_amdgcn_mfma_f32_16x16x32_f16(a, b, c, 0, 0, 0);
}

// one group of NT m-tiles, this wave's 8 n-tiles; layout-agnostic via rowslot/colslot
template<int NT>
__device__ __forceinline__ void process_group(
    int mstart, const float* __restrict__ xb, const float* __restrict__ pos,
    const half8* w1s, const float4* w2s, float* attw,
    int wave, int lane, int q, int c,
    const int* rowslot, const int* colslot, int path)
{
    // --- A fragments: x+pos -> fp16; slot c carries sequence row (mstart+t)*16 + c ---
    half8 af[NT][4];
#pragma unroll
    for (int t = 0; t < NT; ++t) {
        int row = (mstart + t) * 16 + c;
        bool ok = row < SS;
        const float4* xr = (const float4*)(xb + row * HH);
        const float4* pr = (const float4*)(pos + row * HH);
#pragma unroll
        for (int ks = 0; ks < 4; ++ks) {
            int ci = ks * 8 + q * 2;
            float4 x0, x1, p0, p1;
            if (ok) { x0 = xr[ci]; x1 = xr[ci + 1]; p0 = pr[ci]; p1 = pr[ci + 1]; }
            else {
                x0 = make_float4(0.f,0.f,0.f,0.f); x1 = x0; p0 = x0; p1 = x0;
            }
            half8 h;
            h[0] = (_Float16)(x0.x + p0.x); h[1] = (_Float16)(x0.y + p0.y);
            h[2] = (_Float16)(x0.z + p0.z); h[3] = (_Float16)(x0.w + p0.w);
            h[4] = (_Float16)(x1.x + p1.x); h[5] = (_Float16)(x1.y + p1.y);
            h[6] = (_Float16)(x1.z + p1.z); h[7] = (_Float16)(x1.w + p1.w);
            af[t][ks] = h;
        }
    }

    float attp[NT][4][NHD];
#pragma unroll
    for (int t = 0; t < NT; ++t)
#pragma unroll
        for (int r = 0; r < 4; ++r)
#pragma unroll
            for (int k = 0; k < NHD; ++k) attp[t][r][k] = 0.0f;

    int nt0 = wave * 8;
    for (int nt = nt0; nt < nt0 + 8; ++nt) {
        float4 w2v[4];
#pragma unroll
        for (int r = 0; r < 4; ++r) w2v[r] = w2s[nt * 16 + colslot[r]];
        half8 bf[4];
#pragma unroll
        for (int ks = 0; ks < 4; ++ks) bf[ks] = w1s[(nt * 4 + ks) * 64 + lane];
        f32x4 acc[NT];
#pragma unroll
        for (int t = 0; t < NT; ++t) { f32x4 z = {0.f,0.f,0.f,0.f}; acc[t] = z; }
#pragma unroll
        for (int ks = 0; ks < 4; ++ks)
#pragma unroll
            for (int t = 0; t < NT; ++t)
                acc[t] = mfma16(af[t][ks], bf[ks], acc[t]);
        // element (r,lane) holds hidden[(mstart+t)*16+rowslot[r]][nt*16+colslot[r]]
#pragma unroll
        for (int t = 0; t < NT; ++t)
#pragma unroll
            for (int r = 0; r < 4; ++r) {
                float h = tanh_fast(acc[t][r]);
                attp[t][r][0] += h * w2v[r].x;
                attp[t][r][1] += h * w2v[r].y;
                attp[t][r][2] += h * w2v[r].z;
                attp[t][r][3] += h * w2v[r].w;
            }
    }

    if (path == 0) {
        // guide map: rowslot[r]=q*4+r, colslot[r]=c — sum the 16 c-slots via xor 1,2,4,8
#pragma unroll
        for (int t = 0; t < NT; ++t)
#pragma unroll
            for (int r = 0; r < 4; ++r)
#pragma unroll
                for (int k = 0; k < NHD; ++k) {
                    float v = attp[t][r][k];
                    v += __shfl_xor(v, 1);
                    v += __shfl_xor(v, 2);
                    v += __shfl_xor(v, 4);
                    v += __shfl_xor(v, 8);
                    if (c == 0)
                        atomicAdd(&attw[((mstart + t) * 16 + rowslot[r]) * NHD + k], v);
                }
    } else if (path == 1) {
        // swapped map: rowslot[r]=c, colslot[r]=q*4+r — sum r locally, xor 16,32 over q
#pragma unroll
        for (int t = 0; t < NT; ++t)
#pragma unroll
            for (int k = 0; k < NHD; ++k) {
                float v = attp[t][0][k] + attp[t][1][k] + attp[t][2][k] + attp[t][3][k];
                v += __shfl_xor(v, 16);
                v += __shfl_xor(v, 32);
                if (q == 0)
                    atomicAdd(&attw[((mstart + t) * 16 + c) * NHD + k], v);
            }
    } else {
        // generic fallback: per-lane atomics, correct for any bijective map
#pragma unroll
        for (int t = 0; t < NT; ++t)
#pragma unroll
            for (int r = 0; r < 4; ++r)
#pragma unroll
                for (int k = 0; k < NHD; ++k)
                    atomicAdd(&attw[((mstart + t) * 16 + rowslot[r]) * NHD + k],
                              attp[t][r][k]);
    }
}

__global__ __launch_bounds__(256, 1)
void mhan_main(const float* __restrict__ item, const int* __restrict__ mask,
               const float* __restrict__ pos, const float* __restrict__ W1,
               const float* __restrict__ W2, const _Float16* __restrict__ w1sw,
               int use_ws, float* __restrict__ out)
{
    __shared__ half8  w1s[NTILES * 4 * 64];   // 131072 B
    __shared__ float4 w2s[FH];                // 8192 B
    __shared__ float  attw[208 * NHD];        // 3328 B

    int tid = threadIdx.x;
    int b   = blockIdx.x;
    int lane = tid & 63, wave = tid >> 6;
    int q = lane >> 4, c = lane & 15;

    // ---- layout probe: 2 exact MFMAs reveal each C element's true (row,col) source slots ----
    int rowslot[4], colslot[4];
    {
        half8 pc_, pone;
#pragma unroll
        for (int j = 0; j < 8; ++j) { pc_[j] = (_Float16)(float)c; pone[j] = (_Float16)0.03125f; }
        f32x4 z = {0.f,0.f,0.f,0.f};
        f32x4 pr = mfma16(pc_, pone, z);   // value = source A-slot (row provenance)
        f32x4 pcv = mfma16(pone, pc_, z);  // value = source B-slot (col provenance)
#pragma unroll
        for (int r = 0; r < 4; ++r) {
            int rv = (int)(pr[r] + 0.5f);
            int cv = (int)(pcv[r] + 0.5f);
            rowslot[r] = rv < 0 ? 0 : (rv > 15 ? 15 : rv);
            colslot[r] = cv < 0 ? 0 : (cv > 15 ? 15 : cv);
        }
    }
    int okA = 1, okB = 1;
#pragma unroll
    for (int r = 0; r < 4; ++r) {
        okA &= (rowslot[r] == q * 4 + r) & (colslot[r] == c);
        okB &= (rowslot[r] == c) & (colslot[r] == q * 4 + r);
    }
    int path = __all(okA) ? 0 : (__all(okB) ? 1 : 2);

    // ---- stage W1 (fp16 fragment-linear), W2, zero att ----
    if (use_ws) {
        const half8* src = (const half8*)w1sw;
        for (int i = tid; i < NTILES * 4 * 64; i += 256) w1s[i] = src[i];
    } else {
        _Float16* w1f = (_Float16*)w1s;
        for (int idx = tid; idx < HH * FH; idx += 256) {
            int j = idx & 7; int ln = (idx >> 3) & 63;
            int ks = (idx >> 9) & 3; int nt = idx >> 11;
            int k = ks * 32 + (ln >> 4) * 8 + j;
            int n = nt * 16 + (ln & 15);
            w1f[idx] = (_Float16)W1[k * FH + n];
        }
    }
    for (int i = tid; i < FH; i += 256) w2s[i] = ((const float4*)W2)[i];
    for (int i = tid; i < 208 * NHD; i += 256) attw[i] = 0.0f;
    __syncthreads();

    const float* xb = item + (size_t)b * SS * HH;

    process_group<4>(0,  xb, pos, w1s, w2s, attw, wave, lane, q, c, rowslot, colslot, path);
    process_group<3>(4,  xb, pos, w1s, w2s, attw, wave, lane, q, c, rowslot, colslot, path);
    process_group<3>(7,  xb, pos, w1s, w2s, attw, wave, lane, q, c, rowslot, colslot, path);
    process_group<3>(10, xb, pos, w1s, w2s, attw, wave, lane, q, c, rowslot, colslot, path);
    __syncthreads();

    // ---- masked softmax over S; head k = wave ----
    {
        int k = wave;
        float l[4];
        float m = -__builtin_inff();
#pragma unroll
        for (int i = 0; i < 4; ++i) {
            int s = lane + i * 64;
            if (s < SS) {
                float lv = (mask[(size_t)b * SS + s] != 0) ? attw[s * NHD + k] : NEGF;
                l[i] = lv;
                m = fmaxf(m, lv);
            } else {
                l[i] = -__builtin_inff();
            }
        }
#pragma unroll
        for (int off = 32; off >= 1; off >>= 1) m = fmaxf(m, __shfl_xor(m, off));
        float e[4], sum = 0.0f;
#pragma unroll
        for (int i = 0; i < 4; ++i) {
            e[i] = (l[i] == -__builtin_inff()) ? 0.0f : __expf(l[i] - m);
            sum += e[i];
        }
#pragma unroll
        for (int off = 32; off >= 1; off >>= 1) sum += __shfl_xor(sum, off);
        float inv = __builtin_amdgcn_rcpf(sum);
#pragma unroll
        for (int i = 0; i < 4; ++i) {
            int s = lane + i * 64;
            if (s < SS) attw[s * NHD + k] = e[i] * inv;
        }
    }
    // wave k wrote only column k; wave k reads only column k below — same-wave DS order suffices

    // ---- interest[k][h] = sum_s w[s,k] * x[s,h]  (fp32 out — reference output is float32) ----
    {
        int k = wave;
        float ax = 0.0f, ay = 0.0f;
#pragma unroll 8
        for (int s = 0; s < SS; ++s) {
            float w = attw[s * NHD + k];
            float2 xv = ((const float2*)(xb + s * HH))[lane];
            ax += w * xv.x;
            ay += w * xv.y;
        }
        size_t o = ((size_t)b * NHD + k) * HH + lane * 2;
        float2 ov; ov.x = ax; ov.y = ay;
        *(float2*)(out + o) = ov;
    }
}

extern "C" void kernel_launch(void* const* d_in, const int* in_sizes, int n_in,
                              void* d_out, int out_size, void* d_ws, size_t ws_size,
                              hipStream_t stream) {
    const float* item = (const float*)d_in[0];
    const int*   mask = (const int*)d_in[1];
    const float* pos  = (const float*)d_in[2];
    const float* W1   = (const float*)d_in[3];
    const float* W2   = (const float*)d_in[4];
    float* out = (float*)d_out;

    int B = in_sizes[0] / (SS * HH);
    int use_ws = (ws_size >= (size_t)(HH * FH * sizeof(_Float16))) ? 1 : 0;

    if (use_ws) {
        hipLaunchKernelGGL(swizzle_w1, dim3((HH * FH) / 256), dim3(256), 0, stream,
                           W1, (_Float16*)d_ws);
    }
    hipLaunchKernelGGL(mhan_main, dim3(B), dim3(256), 0, stream,
                       item, mask, pos, W1, W2, (const _Float16*)d_ws, use_ws, out);
}